// Round 12
// baseline (164.134 us; speedup 1.0000x reference)
//
#include <hip/hip_runtime.h>
#include <stdint.h>

// VectorQuantize: x (8,256,32,32) f32, embed_w (4096,256) f32
// M = 8192 rows, K = 4096 codes, d = 256
// out (floats): [0,2097152) x_q (b,c,h,w); [2097152] loss; [2097153,2105345) embed_ind
//
// Round 12: prep byte-identical to R10/R11. Gemm v3: 256m x 128k block (grid
// 32x32), wave = 128m x 64k, SAME 16x16x32 MFMA + same swizzle math as the
// proven R8/R11 kernel — only the M-extent per wave doubles, halving the
// B-fragment L2 traffic (the largest measured stall term, ~15.5us). vq_out:
// 1024 blocks (32-c chunks) for gather latency hiding.

typedef _Float16 f16;
typedef f16 half8 __attribute__((ext_vector_type(8)));
typedef float f32x4 __attribute__((ext_vector_type(4)));

__device__ __forceinline__ unsigned int sortable_f32(float v) {
    unsigned int u = __float_as_uint(v);
    return (u & 0x80000000u) ? ~u : (u | 0x80000000u);
}

__device__ __forceinline__ void gload_lds16(const void* g, void* l) {
    __builtin_amdgcn_global_load_lds(
        (const __attribute__((address_space(1))) unsigned int*)g,
        (__attribute__((address_space(3))) unsigned int*)l, 16, 0, 0);
}

// ================= K1: all prep, race-free unit partition (grid 1152) =================
__global__ void vq_prep(const float* __restrict__ x, const float* __restrict__ ew,
                        float* __restrict__ e2, float* __restrict__ negx2,
                        unsigned long long* __restrict__ cand,
                        f16* __restrict__ ehi, f16* __restrict__ elo,
                        f16* __restrict__ xhi, f16* __restrict__ xlo,
                        float* __restrict__ loss_cell) {
    __shared__ float xs[32][132];
    const int u = blockIdx.x, tid = threadIdx.x;
    if (u < 512) {
        // e-split (x 2^12, exact) into swizzled planes
        const int t = u * 256 + tid;            // 131072 = 4096 k * 32 groups
        const int k = t >> 5, g32 = t & 31;
        const float4 v0 = *(const float4*)(ew + k * 256 + g32 * 8);
        const float4 v1 = *(const float4*)(ew + k * 256 + g32 * 8 + 4);
        const float vf[8] = {v0.x, v0.y, v0.z, v0.w, v1.x, v1.y, v1.z, v1.w};
        half8 h1, h2;
#pragma unroll
        for (int j = 0; j < 8; ++j) {
            const float v = vf[j] * 4096.0f;    // exact (power of 2)
            const f16 a = (f16)v;
            const f16 b = (f16)(v - (float)a);  // exact in fp32
            h1[j] = a; h2[j] = b;
        }
        const int kt = k >> 7, kk = k & 127, ci = g32 >> 2, g = g32 & 3;
        const long off = ((long)((kt * 8 + ci) * 128 + kk)) * 32 + ((g ^ (kk & 3)) * 8);
        *(half8*)(ehi + off) = h1;
        *(half8*)(elo + off) = h2;
    } else if (u < 544) {
        // e2: same float4 loop as all passing rounds, spread over 32 blocks
        if (tid < 128) {
            const int k = (u - 512) * 128 + tid;
            const float4* row = (const float4*)(ew + k * 256);
            float s = 0.0f;
#pragma unroll 8
            for (int i = 0; i < 64; ++i) {
                float4 v = row[i];
                s += v.x * v.x + v.y * v.y + v.z * v.z + v.w * v.w;
            }
            e2[k] = s;
        }
    } else if (u < 576) {
        const int z = (u - 544) * 256 + tid;    // 8192
        cand[z] = 0ull;
        if (z == 0) *loss_cell = 0.0f;
    } else if (u < 640) {
        // negx2: one row per thread, IDENTICAL per-row c order (bit-exact invariant)
        if (tid < 128) {
            const int r = (u - 576) * 128 + tid;
            const int b = r >> 10, n = r & 1023;
            const float* px = x + b * 262144 + n;
            float s = 0.0f;
#pragma unroll 16
            for (int c = 0; c < 256; ++c) {
                float v = px[c << 10];
                s += v * v;
            }
            negx2[r] = -s;
        }
    } else {
        // x-split: transpose (b,c,n)->(m,d) + fp16 split into swizzled planes
        const int unit = u - 640;               // 0..511
        const int ci = unit & 7, mt = unit >> 3;
        const int b = mt >> 3, n0 = (mt & 7) * 128, c0 = ci * 32;
#pragma unroll
        for (int it = 0; it < 4; ++it) {
            const int idx = tid + it * 256;
            const int cc = idx >> 5, nn4 = idx & 31;
            float4 v = *(const float4*)(x + b * 262144 + (c0 + cc) * 1024 + n0 + nn4 * 4);
            *(float4*)&xs[cc][nn4 * 4] = v;
        }
        __syncthreads();
#pragma unroll
        for (int it = 0; it < 2; ++it) {
            const int idx = tid + it * 256;
            const int mm = idx & 127, g = idx >> 7;
            half8 h1, h2;
#pragma unroll
            for (int j = 0; j < 8; ++j) {
                const float v = xs[g * 8 + j][mm];
                const f16 a = (f16)v;
                const f16 bb = (f16)(v - (float)a);
                h1[j] = a; h2[j] = bb;
            }
            const long off = ((long)((mt * 8 + ci) * 128 + mm)) * 32 + ((g ^ (mm & 3)) * 8);
            *(half8*)(xhi + off) = h1;
            *(half8*)(xlo + off) = h2;
        }
    }
}

// ================= K2: gemm v3 — 256m x 128k block, wave = 128m x 64k =================
// Same MFMA shape / swizzle / numerics as R11; M-extent doubled to halve B-L2 traffic.
__launch_bounds__(256, 2)
__global__ void vq_gemm(const f16* __restrict__ xhi, const f16* __restrict__ xlo,
                        const f16* __restrict__ ehi, const f16* __restrict__ elo,
                        const float* __restrict__ e2, const float* __restrict__ negx2,
                        unsigned long long* __restrict__ cand) {
    // halves: hi-t0 [0,4096) | hi-t1 [4096,8192) | lo-t0 [8192,12288) | lo-t1 [12288,16384)
    __shared__ __align__(16) f16 lds[16384];   // 32 KB
    const int tid = threadIdx.x;
    const int kt = blockIdx.x, mtb = blockIdx.y;   // mtb: 256-row tile, 0..31
    const int lane = tid & 63, wave = tid >> 6;
    const int wm = wave >> 1, wk = wave & 1;
    const int col = lane & 15, quad = lane >> 4;

    f32x4 acc[8][4] = {};

    // two consecutive 128-row plane tiles: t1 is +32768 halves from t0
    const f16* gxh = xhi + (size_t)(mtb * 16) * 4096;
    const f16* gxl = xlo + (size_t)(mtb * 16) * 4096;
    const f16* geh = ehi + (size_t)(kt * 8) * 4096;
    const f16* gel = elo + (size_t)(kt * 8) * 4096;

    int aoff[8], boff[4];
#pragma unroll
    for (int i = 0; i < 8; ++i) {
        const int lr = i * 16 + col;               // local row within the wave's 128-tile
        aoff[i] = wm * 4096 + lr * 32 + ((quad ^ (lr & 3)) * 8);
    }
#pragma unroll
    for (int j = 0; j < 4; ++j) {
        const int k = wk * 64 + j * 16 + col;
        boff[j] = k * 32 + ((quad ^ (k & 3)) * 8);
    }

    for (int ci = 0; ci < 8; ++ci) {
        __syncthreads();
        const int go = ci * 4096 + tid * 8;        // halves within a tile's plane
        char* lb = (char*)lds + wave * 1024;       // wave-uniform dst base
        // hi t0 -> [0,8KB), hi t1 -> [8KB,16KB), lo t0 -> [16KB,24KB), lo t1 -> [24KB,32KB)
        gload_lds16(gxh + go,                 lb);
        gload_lds16(gxh + go + 2048,          lb + 4096);
        gload_lds16(gxh + go + 32768,         lb + 8192);
        gload_lds16(gxh + go + 32768 + 2048,  lb + 12288);
        gload_lds16(gxl + go,                 lb + 16384);
        gload_lds16(gxl + go + 2048,          lb + 20480);
        gload_lds16(gxl + go + 32768,         lb + 24576);
        gload_lds16(gxl + go + 32768 + 2048,  lb + 28672);
        // B fragments: direct global loads (L2-resident, coalesced via baked XOR swizzle)
        half8 bhi4[4], blo4[4];
#pragma unroll
        for (int j = 0; j < 4; ++j) {
            bhi4[j] = *(const half8*)(geh + ci * 4096 + boff[j]);
            blo4[j] = *(const half8*)(gel + ci * 4096 + boff[j]);
        }
        __syncthreads();

#pragma unroll
        for (int i = 0; i < 8; ++i) {
            const half8 ah = *(const half8*)&lds[aoff[i]];
            const half8 al = *(const half8*)&lds[8192 + aoff[i]];
#pragma unroll
            for (int j = 0; j < 4; ++j) {
                acc[i][j] = __builtin_amdgcn_mfma_f32_16x16x32_f16(ah, bhi4[j], acc[i][j], 0, 0, 0);
                acc[i][j] = __builtin_amdgcn_mfma_f32_16x16x32_f16(ah, blo4[j], acc[i][j], 0, 0, 0);
                acc[i][j] = __builtin_amdgcn_mfma_f32_16x16x32_f16(al, bhi4[j], acc[i][j], 0, 0, 0);
            }
        }
    }

    // epilogue: C layout col=lane&15, row=quad*4+reg
    const int m0 = mtb * 256 + wm * 128, k0 = kt * 128 + wk * 64;
#pragma unroll
    for (int i = 0; i < 8; ++i)
#pragma unroll
        for (int r = 0; r < 4; ++r) {
            const float A = negx2[m0 + i * 16 + quad * 4 + r];
            unsigned long long bk = 0ull;
#pragma unroll
            for (int j = 0; j < 4; ++j) {
                const int k = k0 + j * 16 + col;
                const float t1 = A - e2[k];                        // rounding 1
                const float dist = t1 + acc[i][j][r] * 0x1p-11f;   // exact scale; rounding 2
                const unsigned long long key =
                    ((unsigned long long)sortable_f32(dist) << 32)
                    | (unsigned long long)(unsigned int)(4095 - k);
                if (key > bk) bk = key;
            }
#pragma unroll
            for (int mask = 1; mask <= 8; mask <<= 1) {
                const unsigned long long o = __shfl_xor(bk, mask, 64);
                if (o > bk) bk = o;
            }
            if (col == ((i * 4 + r) & 15))
                atomicMax(&cand[m0 + i * 16 + quad * 4 + r], bk);
        }
}

// ================= K3: gather + transposed x_q store + ind + loss-from-cand =================
__global__ void vq_out(const float* __restrict__ ew,
                       const unsigned long long* __restrict__ cand,
                       float* __restrict__ out) {
    __shared__ int sidx[64];
    const int tid = threadIdx.x;
    const int r0 = blockIdx.x * 64;
    const int cq0 = blockIdx.y * 32;
    const int b = r0 >> 10, n0 = r0 & 1023;

    if (tid < 64) {
        const int r = r0 + tid;
        const unsigned long long bk = cand[r];
        const int idx = 4095 - (int)(unsigned int)(bk & 0xFFFFFFFFull);
        sidx[tid] = idx;
        if (blockIdx.y == 0) {
            out[2097153 + r] = (float)idx;
            // decode dist (always negative): -dist == ||x-e||^2 for this row
            const unsigned int s = (unsigned int)(bk >> 32);
            const unsigned int ubits = (s & 0x80000000u) ? (s & 0x7FFFFFFFu) : ~s;
            float nd = -__uint_as_float(ubits);
#pragma unroll
            for (int m = 1; m <= 32; m <<= 1) nd += __shfl_xor(nd, m, 64);
            if (tid == 0)
                atomicAdd(&out[2097152], 1.25f * (nd / 2097152.0f));
        }
    }
    __syncthreads();

    const int nn = tid & 63, cq = tid >> 6;
    const float* erow = ew + (size_t)sidx[nn] * 256 + cq0;
    float* ocol = out + (size_t)b * 262144 + ((size_t)cq0 << 10) + n0 + nn;
#pragma unroll
    for (int cb = 0; cb < 8; ++cb) {
        const int c = cb * 4 + cq;
        ocol[(size_t)c << 10] = erow[c];    // stores coalesced along nn
    }
}

extern "C" void kernel_launch(void* const* d_in, const int* in_sizes, int n_in,
                              void* d_out, int out_size, void* d_ws, size_t ws_size,
                              hipStream_t stream) {
    const float* x  = (const float*)d_in[0];
    const float* ew = (const float*)d_in[1];
    float* out = (float*)d_out;

    float* e2 = (float*)d_ws;                                              // 16 KB
    float* negx2 = e2 + 4096;                                              // 32 KB
    unsigned long long* cand = (unsigned long long*)((char*)d_ws + 49152); // 64 KB
    f16* ehi = (f16*)((char*)d_ws + 114688);                               // 2 MB (4K-aligned)
    f16* elo = (f16*)((char*)d_ws + 114688 + 2097152);                     // 2 MB
    f16* xhi = (f16*)out;                                                  // x_q region scratch
    f16* xlo = (f16*)(out + 1048576);

    vq_prep<<<1152, 256, 0, stream>>>(x, ew, e2, negx2, cand,
                                      ehi, elo, xhi, xlo, out + 2097152);
    vq_gemm<<<dim3(32, 32), 256, 0, stream>>>(xhi, xlo, ehi, elo, e2, negx2, cand);
    vq_out<<<dim3(128, 8), 256, 0, stream>>>(ew, cand, out);
}

// Round 13
// 146.839 us; speedup vs baseline: 1.1178x; 1.1178x over previous
//
#include <hip/hip_runtime.h>
#include <stdint.h>

// VectorQuantize: x (8,256,32,32) f32, embed_w (4096,256) f32
// M = 8192 rows, K = 4096 codes, d = 256
// out (floats): [0,2097152) x_q (b,c,h,w); [2097152] loss; [2097153,2105345) embed_ind
//
// Round 13: restore R11 exactly — the measured optimum of this decomposition.
//   K1 vq_prep (1152 blocks): e-split, e2, negx2, zero, x-split (race-free units)
//   K2 vq_gemm (32x64): split-fp16 16x16x32 MFMA, 128x128 tiles, A via LDS DMA,
//      B frags direct global->VGPR (L2-resident, XOR-swizzle-coalesced)
//   K3 vq_out (128x4): gather + transposed x_q + ind + loss decoded from cand keys
// Structural ceilings (measured): gemm 67us = m97-family plateau (R3/R9/R12
// variants regressed); 3 launches minimal (R4/R5/R7 fusion attempts regressed).

typedef _Float16 f16;
typedef f16 half8 __attribute__((ext_vector_type(8)));
typedef float f32x4 __attribute__((ext_vector_type(4)));

__device__ __forceinline__ unsigned int sortable_f32(float v) {
    unsigned int u = __float_as_uint(v);
    return (u & 0x80000000u) ? ~u : (u | 0x80000000u);
}

__device__ __forceinline__ void gload_lds16(const void* g, void* l) {
    __builtin_amdgcn_global_load_lds(
        (const __attribute__((address_space(1))) unsigned int*)g,
        (__attribute__((address_space(3))) unsigned int*)l, 16, 0, 0);
}

// ================= K1: all prep, race-free unit partition (grid 1152) =================
__global__ void vq_prep(const float* __restrict__ x, const float* __restrict__ ew,
                        float* __restrict__ e2, float* __restrict__ negx2,
                        unsigned long long* __restrict__ cand,
                        f16* __restrict__ ehi, f16* __restrict__ elo,
                        f16* __restrict__ xhi, f16* __restrict__ xlo,
                        float* __restrict__ loss_cell) {
    __shared__ float xs[32][132];
    const int u = blockIdx.x, tid = threadIdx.x;
    if (u < 512) {
        // e-split (x 2^12, exact) into swizzled planes
        const int t = u * 256 + tid;            // 131072 = 4096 k * 32 groups
        const int k = t >> 5, g32 = t & 31;
        const float4 v0 = *(const float4*)(ew + k * 256 + g32 * 8);
        const float4 v1 = *(const float4*)(ew + k * 256 + g32 * 8 + 4);
        const float vf[8] = {v0.x, v0.y, v0.z, v0.w, v1.x, v1.y, v1.z, v1.w};
        half8 h1, h2;
#pragma unroll
        for (int j = 0; j < 8; ++j) {
            const float v = vf[j] * 4096.0f;    // exact (power of 2)
            const f16 a = (f16)v;
            const f16 b = (f16)(v - (float)a);  // exact in fp32
            h1[j] = a; h2[j] = b;
        }
        const int kt = k >> 7, kk = k & 127, ci = g32 >> 2, g = g32 & 3;
        const long off = ((long)((kt * 8 + ci) * 128 + kk)) * 32 + ((g ^ (kk & 3)) * 8);
        *(half8*)(ehi + off) = h1;
        *(half8*)(elo + off) = h2;
    } else if (u < 544) {
        // e2: same float4 loop as all passing rounds, spread over 32 blocks
        if (tid < 128) {
            const int k = (u - 512) * 128 + tid;
            const float4* row = (const float4*)(ew + k * 256);
            float s = 0.0f;
#pragma unroll 8
            for (int i = 0; i < 64; ++i) {
                float4 v = row[i];
                s += v.x * v.x + v.y * v.y + v.z * v.z + v.w * v.w;
            }
            e2[k] = s;
        }
    } else if (u < 576) {
        const int z = (u - 544) * 256 + tid;    // 8192
        cand[z] = 0ull;
        if (z == 0) *loss_cell = 0.0f;
    } else if (u < 640) {
        // negx2: one row per thread, IDENTICAL per-row c order (bit-exact invariant)
        if (tid < 128) {
            const int r = (u - 576) * 128 + tid;
            const int b = r >> 10, n = r & 1023;
            const float* px = x + b * 262144 + n;
            float s = 0.0f;
#pragma unroll 16
            for (int c = 0; c < 256; ++c) {
                float v = px[c << 10];
                s += v * v;
            }
            negx2[r] = -s;
        }
    } else {
        // x-split: transpose (b,c,n)->(m,d) + fp16 split into swizzled planes
        const int unit = u - 640;               // 0..511
        const int ci = unit & 7, mt = unit >> 3;
        const int b = mt >> 3, n0 = (mt & 7) * 128, c0 = ci * 32;
#pragma unroll
        for (int it = 0; it < 4; ++it) {
            const int idx = tid + it * 256;
            const int cc = idx >> 5, nn4 = idx & 31;
            float4 v = *(const float4*)(x + b * 262144 + (c0 + cc) * 1024 + n0 + nn4 * 4);
            *(float4*)&xs[cc][nn4 * 4] = v;
        }
        __syncthreads();
#pragma unroll
        for (int it = 0; it < 2; ++it) {
            const int idx = tid + it * 256;
            const int mm = idx & 127, g = idx >> 7;
            half8 h1, h2;
#pragma unroll
            for (int j = 0; j < 8; ++j) {
                const float v = xs[g * 8 + j][mm];
                const f16 a = (f16)v;
                const f16 bb = (f16)(v - (float)a);
                h1[j] = a; h2[j] = bb;
            }
            const long off = ((long)((mt * 8 + ci) * 128 + mm)) * 32 + ((g ^ (mm & 3)) * 8);
            *(half8*)(xhi + off) = h1;
            *(half8*)(xlo + off) = h2;
        }
    }
}

// ================= K2: gemm — R8/R11's proven version, byte-for-byte =================
__launch_bounds__(256, 2)
__global__ void vq_gemm(const f16* __restrict__ xhi, const f16* __restrict__ xlo,
                        const f16* __restrict__ ehi, const f16* __restrict__ elo,
                        const float* __restrict__ e2, const float* __restrict__ negx2,
                        unsigned long long* __restrict__ cand) {
    __shared__ __align__(16) f16 lds[8192];   // 16 KB: xhi | xlo, 4096 halves each
    const int tid = threadIdx.x;
    const int kt = blockIdx.x, mt = blockIdx.y;
    const int lane = tid & 63, wave = tid >> 6;
    const int wm = wave >> 1, wk = wave & 1;
    const int col = lane & 15, quad = lane >> 4;

    f32x4 acc[4][4] = {};

    const f16* gx[2] = { xhi + (size_t)(mt * 8) * 4096, xlo + (size_t)(mt * 8) * 4096 };
    const f16* geh = ehi + (size_t)(kt * 8) * 4096;
    const f16* gel = elo + (size_t)(kt * 8) * 4096;

    int aoff[4], boff[4];
#pragma unroll
    for (int i = 0; i < 4; ++i) {
        const int m = wm * 64 + i * 16 + col;
        aoff[i] = m * 32 + ((quad ^ (m & 3)) * 8);
        const int k = wk * 64 + i * 16 + col;
        boff[i] = k * 32 + ((quad ^ (k & 3)) * 8);   // same XOR layout baked into planes
    }

    for (int ci = 0; ci < 8; ++ci) {
        __syncthreads();
        const int go = ci * 4096 + tid * 8;             // halves
        char* lb = (char*)lds + wave * 1024;            // wave-uniform dst base
#pragma unroll
        for (int p = 0; p < 2; ++p) {
            gload_lds16(gx[p] + go,        lb + p * 8192);
            gload_lds16(gx[p] + go + 2048, lb + p * 8192 + 4096);
        }
        // B fragments: direct global loads (L2-resident e-planes, fully coalesced
        // via the XOR swizzle baked into the plane layout)
        half8 bhi4[4], blo4[4];
#pragma unroll
        for (int j = 0; j < 4; ++j) {
            bhi4[j] = *(const half8*)(geh + ci * 4096 + boff[j]);
            blo4[j] = *(const half8*)(gel + ci * 4096 + boff[j]);
        }
        __syncthreads();

        half8 ahi4[4], alo4[4];
#pragma unroll
        for (int i = 0; i < 4; ++i) {
            ahi4[i] = *(const half8*)&lds[aoff[i]];
            alo4[i] = *(const half8*)&lds[4096 + aoff[i]];
        }
#pragma unroll
        for (int i = 0; i < 4; ++i)
#pragma unroll
            for (int j = 0; j < 4; ++j) {
                acc[i][j] = __builtin_amdgcn_mfma_f32_16x16x32_f16(ahi4[i], bhi4[j], acc[i][j], 0, 0, 0);
                acc[i][j] = __builtin_amdgcn_mfma_f32_16x16x32_f16(ahi4[i], blo4[j], acc[i][j], 0, 0, 0);
                acc[i][j] = __builtin_amdgcn_mfma_f32_16x16x32_f16(alo4[i], bhi4[j], acc[i][j], 0, 0, 0);
            }
    }

    // epilogue: C layout col=lane&15, row=quad*4+reg
    const int m0 = mt * 128 + wm * 64, k0 = kt * 128 + wk * 64;
#pragma unroll
    for (int i = 0; i < 4; ++i)
#pragma unroll
        for (int r = 0; r < 4; ++r) {
            const float A = negx2[m0 + i * 16 + quad * 4 + r];
            unsigned long long bk = 0ull;
#pragma unroll
            for (int j = 0; j < 4; ++j) {
                const int k = k0 + j * 16 + col;
                const float t1 = A - e2[k];                        // rounding 1
                const float dist = t1 + acc[i][j][r] * 0x1p-11f;   // exact scale; rounding 2
                const unsigned long long key =
                    ((unsigned long long)sortable_f32(dist) << 32)
                    | (unsigned long long)(unsigned int)(4095 - k);
                if (key > bk) bk = key;
            }
#pragma unroll
            for (int mask = 1; mask <= 8; mask <<= 1) {
                const unsigned long long o = __shfl_xor(bk, mask, 64);
                if (o > bk) bk = o;
            }
            if (col == i * 4 + r)
                atomicMax(&cand[m0 + i * 16 + quad * 4 + r], bk);
        }
}

// ================= K3: gather + transposed x_q store + ind + loss-from-cand =================
__global__ void vq_out(const float* __restrict__ ew,
                       const unsigned long long* __restrict__ cand,
                       float* __restrict__ out) {
    __shared__ int sidx[64];
    const int tid = threadIdx.x;
    const int r0 = blockIdx.x * 64;
    const int cq0 = blockIdx.y * 64;
    const int b = r0 >> 10, n0 = r0 & 1023;

    if (tid < 64) {
        const int r = r0 + tid;
        const unsigned long long bk = cand[r];
        const int idx = 4095 - (int)(unsigned int)(bk & 0xFFFFFFFFull);
        sidx[tid] = idx;
        if (cq0 == 0) {
            out[2097153 + r] = (float)idx;
            // decode dist (always negative here): -dist == ||x-e||^2 for this row
            const unsigned int s = (unsigned int)(bk >> 32);
            const unsigned int ubits = (s & 0x80000000u) ? (s & 0x7FFFFFFFu) : ~s;
            float nd = -__uint_as_float(ubits);
#pragma unroll
            for (int m = 1; m <= 32; m <<= 1) nd += __shfl_xor(nd, m, 64);
            if (tid == 0)
                atomicAdd(&out[2097152], 1.25f * (nd / 2097152.0f));
        }
    }
    __syncthreads();

    const int nn = tid & 63, cq = tid >> 6;
    const float* erow = ew + (size_t)sidx[nn] * 256 + cq0;
    float* ocol = out + (size_t)b * 262144 + ((size_t)cq0 << 10) + n0 + nn;
#pragma unroll
    for (int cb = 0; cb < 16; ++cb) {
        const int c = cb * 4 + cq;
        ocol[(size_t)c << 10] = erow[c];    // stores coalesced along nn
    }
}

extern "C" void kernel_launch(void* const* d_in, const int* in_sizes, int n_in,
                              void* d_out, int out_size, void* d_ws, size_t ws_size,
                              hipStream_t stream) {
    const float* x  = (const float*)d_in[0];
    const float* ew = (const float*)d_in[1];
    float* out = (float*)d_out;

    float* e2 = (float*)d_ws;                                              // 16 KB
    float* negx2 = e2 + 4096;                                              // 32 KB
    unsigned long long* cand = (unsigned long long*)((char*)d_ws + 49152); // 64 KB
    f16* ehi = (f16*)((char*)d_ws + 114688);                               // 2 MB (4K-aligned)
    f16* elo = (f16*)((char*)d_ws + 114688 + 2097152);                     // 2 MB
    f16* xhi = (f16*)out;                                                  // x_q region scratch
    f16* xlo = (f16*)(out + 1048576);

    vq_prep<<<1152, 256, 0, stream>>>(x, ew, e2, negx2, cand,
                                      ehi, elo, xhi, xlo, out + 2097152);
    vq_gemm<<<dim3(32, 64), 256, 0, stream>>>(xhi, xlo, ehi, elo, e2, negx2, cand);
    vq_out<<<dim3(128, 4), 256, 0, stream>>>(ew, cand, out);
}